// Round 9
// baseline (122.811 us; speedup 1.0000x reference)
//
#include <hip/hip_runtime.h>

// out = Re[(Fr + i Fi) @ U] as float32[65536,128] (out_size = 8388608 floats).
// U = Clements mesh (128 layers of disjoint 2x2 MZI column rotations) * diag(e^{i oph}).
// Budget (R8): dur_us includes ~67 us harness prep (256 MiB d_ws poison ~42 us
// + input restore/d_out fill ~25 us); ours ~55 us = cgemm ~42 + build ~8 + trig ~3.
// cgemm was occupancy-bound (64 KB LDS -> 2 blocks/CU). This round: NO-LDS cgemm —
// U frags read per-kt straight from global (64 KB image, L2-resident, 1 KB/inst
// coalesced), no barrier, launch_bounds(256,3) -> ~12 waves/CU.
//   k0 trig_k:   8128 MZIs -> (ct*cp, ct*sp, st) float4; pad to 8192.
//   k1 build_u:  128 blocks x 1 wave; block r evolves ROW r of U in registers
//                (lane p owns cols 2p,2p+1; odd layers shfl-exchange; depth-8
//                trig ring, FULL unroll keeps ring in VGPRs).
//   k2 cgemm:    512 blocks x 256 thr (4 waves x 32 rows), Re = Fr*Ur - Fi*Ui.

typedef __attribute__((ext_vector_type(8))) short short8;
typedef __attribute__((ext_vector_type(4))) float float4v;

#define MFMA(a, b, c) __builtin_amdgcn_mfma_f32_16x16x32_bf16((a), (b), (c), 0, 0, 0)

__device__ __forceinline__ unsigned short f2bf(float f) {
    unsigned u = __builtin_bit_cast(unsigned, f);
    u += 0x7FFFu + ((u >> 16) & 1u);   // round-to-nearest-even
    return (unsigned short)(u >> 16);
}

__device__ __forceinline__ short8 pack8(float4v a, float4v b) {
    short8 r;
    r[0] = (short)f2bf(a[0]); r[1] = (short)f2bf(a[1]);
    r[2] = (short)f2bf(a[2]); r[3] = (short)f2bf(a[3]);
    r[4] = (short)f2bf(b[0]); r[5] = (short)f2bf(b[1]);
    r[6] = (short)f2bf(b[2]); r[7] = (short)f2bf(b[3]);
    return r;
}

// ---------------- Kernel 0: per-MZI trig (fully parallel) ----------------
__global__ __launch_bounds__(256) void trig_k(const float* __restrict__ mzi,
                                              float4* __restrict__ trig) {
    const int id = blockIdx.x * 256 + threadIdx.x;
    if (id >= 8192) return;
    if (id < 8128) {
        const float theta = mzi[2 * id], phi = mzi[2 * id + 1];
        float st, ct, sp, cp;
        sincosf(theta, &st, &ct);
        sincosf(phi, &sp, &cp);
        trig[id] = make_float4(ct * cp, ct * sp, st, 0.f);
    } else {
        trig[id] = make_float4(0.f, 0.f, 0.f, 0.f);  // pad (ring loads in-bounds)
    }
}

// ---------------- Kernel 1: build U, one block (1 wave) per row ----------------
// MZI id for (layer l, pair p): (127*l + (l&1))/2 + p   (max 8128 -> padded buf)
__global__ __launch_bounds__(64) void build_u(
    const float* __restrict__ oph, const float4* __restrict__ trig,
    unsigned short* ufrag /* 2 copies x 2 planes x 16384 bf16, frag order */) {
    const int r = blockIdx.x;   // row of U this block owns
    const int p = threadIdx.x;  // lane: owns cols 2p, 2p+1
    float2 c0 = make_float2((2 * p == r) ? 1.f : 0.f, 0.f);
    float2 c1 = make_float2((2 * p + 1 == r) ? 1.f : 0.f, 0.f);

    float4 ring[8];
    #pragma unroll
    for (int i = 0; i < 8; ++i)
        ring[i] = trig[(127 * i + (i & 1)) / 2 + p];

    #pragma unroll   // FULL unroll: ring indices constant -> ring stays in VGPRs
    for (int l = 0; l < 128; ++l) {
        const float4 t = ring[l & 7];
        if (l + 8 < 128)
            ring[l & 7] = trig[(127 * (l + 8) + ((l + 8) & 1)) / 2 + p];
        const float ar = t.x, ai = t.y, s = t.z;
        if ((l & 1) == 0) {
            // pair (2p, 2p+1) = (c0, c1), fully local
            const float2 u = c0, v = c1;
            c0.x = u.x * ar - u.y * ai + v.x * s;
            c0.y = u.x * ai + u.y * ar + v.y * s;
            c1.x = u.x * s - v.x * ar - v.y * ai;
            c1.y = u.y * s + v.x * ai - v.y * ar;
        } else {
            // pair q=p: cols (2p+1, 2p+2) = (my c1, lane p+1's c0)
            const float vx = __shfl_down(c0.x, 1);
            const float vy = __shfl_down(c0.y, 1);
            const float2 u = c1;
            const float nux = u.x * ar - u.y * ai + vx * s;
            const float nuy = u.x * ai + u.y * ar + vy * s;
            const float nvx = u.x * s - vx * ar - vy * ai;
            const float nvy = u.y * s + vx * ai - vy * ar;
            if (p < 63) { c1.x = nux; c1.y = nuy; }   // col 2p+1 update
            const float bx = __shfl_up(nvx, 1);       // col 2p+2 -> lane p+1's c0
            const float by = __shfl_up(nvy, 1);
            if (p > 0) { c0.x = bx; c0.y = by; }      // lane 0 keeps col 0
        }
    }

    // output-phase diagonal + bf16 + scatter into MFMA B-fragment order:
    // B[k][n]: nt=j>>4, lane=(j&15)|(((k>>3)&3)<<4), elem=k&7, kt=k>>5 (k=r,n=j)
    #pragma unroll
    for (int jj = 0; jj < 2; ++jj) {
        const int j = 2 * p + jj;
        const float2 v = (jj == 0) ? c0 : c1;
        float s, c;
        sincosf(oph[j], &s, &c);
        const unsigned short re = f2bf(v.x * c - v.y * s);
        const unsigned short im = f2bf(v.x * s + v.y * c);
        const int nt = j >> 4, kt = r >> 5;
        const int lane = (j & 15) | (((r >> 3) & 3) << 4);
        const int base = (nt * 4 + kt) * 512 + lane * 8 + (r & 7);
        ufrag[base]          = re;   // copy A, plane R
        ufrag[16384 + base]  = im;   // copy A, plane I
        ufrag[32768 + base]  = re;   // copy B, plane R
        ufrag[49152 + base]  = im;   // copy B, plane I
    }
}

// -------- Kernel 2: NO-LDS real-part GEMM (4 waves x 32 rows, N=K=128) --------
// U frags read straight from global (L2-resident 64 KB image), no barriers.
__global__ __launch_bounds__(256, 3) void cgemm_main(
    const float* __restrict__ fr, const float* __restrict__ fi,
    const unsigned short* ufrag, float* out, int maxrow, int rowoff) {
    const int tid = threadIdx.x;
    const int wave = tid >> 6, lane = tid & 63;
    const int lm = lane & 15, lq = lane >> 4;
    const int rowbase = rowoff + blockIdx.x * 128 + wave * 32;

    float4v accR[2][8] = {};

    const size_t abase = (size_t)(rowbase + lm) * 128 + lq * 8;
    const float* pfr = fr + abase;   // mt adds 16 rows = +2048 floats
    const float* pfi = fi + abase;

    const short sgn = (short)0x8000;
    const short8 sgn8 = {sgn, sgn, sgn, sgn, sgn, sgn, sgn, sgn};

    float4v sr[2][2], si[2][2];
    #pragma unroll
    for (int mt = 0; mt < 2; ++mt) {
        sr[mt][0] = *(const float4v*)(pfr + mt * 2048);
        sr[mt][1] = *(const float4v*)(pfr + mt * 2048 + 4);
        si[mt][0] = *(const float4v*)(pfi + mt * 2048);
        si[mt][1] = *(const float4v*)(pfi + mt * 2048 + 4);
    }

    #pragma unroll
    for (int kt = 0; kt < 4; ++kt) {
        short8 afr[2], afin[2];
        #pragma unroll
        for (int mt = 0; mt < 2; ++mt) {
            afr[mt]  = pack8(sr[mt][0], sr[mt][1]);
            afin[mt] = pack8(si[mt][0], si[mt][1]) ^ sgn8;  // -Fi sign flip
        }
        if (kt < 3) {  // prefetch next A k-tile while MFMAs run
            #pragma unroll
            for (int mt = 0; mt < 2; ++mt) {
                sr[mt][0] = *(const float4v*)(pfr + (kt + 1) * 32 + mt * 2048);
                sr[mt][1] = *(const float4v*)(pfr + (kt + 1) * 32 + mt * 2048 + 4);
                si[mt][0] = *(const float4v*)(pfi + (kt + 1) * 32 + mt * 2048);
                si[mt][1] = *(const float4v*)(pfi + (kt + 1) * 32 + mt * 2048 + 4);
            }
        }
        #pragma unroll
        for (int nt = 0; nt < 8; ++nt) {
            const int fo = (nt * 4 + kt) * 512 + lane * 8;
            const short8 ur = *(const short8*)&ufrag[fo];           // global/L2
            const short8 ui = *(const short8*)&ufrag[16384 + fo];   // global/L2
            #pragma unroll
            for (int mt = 0; mt < 2; ++mt) {
                accR[mt][nt] = MFMA(afr[mt],  ur, accR[mt][nt]);
                accR[mt][nt] = MFMA(afin[mt], ui, accR[mt][nt]);
            }
        }
    }

    // epilogue: D layout col = lane&15, row = (lane>>4)*4 + reg
    if (rowbase + 32 <= maxrow) {  // fast path: whole tile in range (always, here)
        #pragma unroll
        for (int mt = 0; mt < 2; ++mt)
            #pragma unroll
            for (int nt = 0; nt < 8; ++nt)
                #pragma unroll
                for (int reg = 0; reg < 4; ++reg)
                    out[(size_t)(rowbase + mt * 16 + lq * 4 + reg) * 128 +
                        nt * 16 + lm] = accR[mt][nt][reg];
    } else {
        #pragma unroll
        for (int mt = 0; mt < 2; ++mt)
            #pragma unroll
            for (int nt = 0; nt < 8; ++nt)
                #pragma unroll
                for (int reg = 0; reg < 4; ++reg) {
                    const int rr = rowbase + mt * 16 + lq * 4 + reg;
                    if (rr < maxrow)
                        out[(size_t)rr * 128 + nt * 16 + lm] = accR[mt][nt][reg];
                }
    }
}

// ---- Fallback-only (d_out staging): LDS-snapshot GEMM for the 2 tail tiles ----
__global__ __launch_bounds__(256, 2) void cgemm_tail(
    const float* __restrict__ fr, const float* __restrict__ fi,
    const unsigned short* ufrag, float* out, int maxrow) {
    __shared__ __align__(16) unsigned short us[32768];
    const int tid = threadIdx.x;
    const unsigned short* ufcopy = ufrag + blockIdx.x * 32768;
    {
        const uint4* g = (const uint4*)ufcopy;
        uint4* l = (uint4*)us;
        #pragma unroll
        for (int i = 0; i < 16; ++i) l[tid + 256 * i] = g[tid + 256 * i];
    }
    __syncthreads();
    const int wave = tid >> 6, lane = tid & 63;
    const int lm = lane & 15, lq = lane >> 4;
    const int rowbase = blockIdx.x * 128 + wave * 32;
    float4v accR[2][8] = {};
    const size_t abase = (size_t)(rowbase + lm) * 128 + lq * 8;
    const float* pfr = fr + abase;
    const float* pfi = fi + abase;
    const short sgn = (short)0x8000;
    const short8 sgn8 = {sgn, sgn, sgn, sgn, sgn, sgn, sgn, sgn};
    #pragma unroll
    for (int kt = 0; kt < 4; ++kt) {
        short8 afr[2], afin[2];
        #pragma unroll
        for (int mt = 0; mt < 2; ++mt) {
            float4v a0 = *(const float4v*)(pfr + kt * 32 + mt * 2048);
            float4v a1 = *(const float4v*)(pfr + kt * 32 + mt * 2048 + 4);
            float4v b0 = *(const float4v*)(pfi + kt * 32 + mt * 2048);
            float4v b1 = *(const float4v*)(pfi + kt * 32 + mt * 2048 + 4);
            afr[mt]  = pack8(a0, a1);
            afin[mt] = pack8(b0, b1) ^ sgn8;
        }
        #pragma unroll
        for (int nt = 0; nt < 8; ++nt) {
            const int fo = (nt * 4 + kt) * 512 + lane * 8;
            const short8 ur = *(const short8*)&us[fo];
            const short8 ui = *(const short8*)&us[16384 + fo];
            #pragma unroll
            for (int mt = 0; mt < 2; ++mt) {
                accR[mt][nt] = MFMA(afr[mt],  ur, accR[mt][nt]);
                accR[mt][nt] = MFMA(afin[mt], ui, accR[mt][nt]);
            }
        }
    }
    #pragma unroll
    for (int mt = 0; mt < 2; ++mt)
        #pragma unroll
        for (int nt = 0; nt < 8; ++nt)
            #pragma unroll
            for (int reg = 0; reg < 4; ++reg) {
                const int rr = rowbase + mt * 16 + lq * 4 + reg;
                if (rr < maxrow)
                    out[(size_t)rr * 128 + nt * 16 + lm] = accR[mt][nt][reg];
            }
}

extern "C" void kernel_launch(void* const* d_in, const int* in_sizes, int n_in,
                              void* d_out, int out_size, void* d_ws, size_t ws_size,
                              hipStream_t stream) {
    const float* fr  = (const float*)d_in[0];
    const float* fi  = (const float*)d_in[1];
    const float* mzi = (const float*)d_in[2];
    const float* oph = (const float*)d_in[3];

    // Capacity in 128-float output rows; clamp by field rows (A-load safety).
    int maxrow = out_size / 128;
    const int arows = in_sizes[0] / 128;
    if (maxrow > arows) maxrow = arows;
    if (maxrow > 65536) maxrow = 65536;

    if (ws_size >= 262144) {
        // Preferred: stage in d_ws (R7/R8 counters: ws ~256 MiB). No tail kernel.
        unsigned short* ufrag = (unsigned short*)d_ws;           // 128 KB (2 copies)
        float4* trig = (float4*)((char*)d_ws + 131072);          // 128 KB
        if (maxrow < 1) return;
        trig_k<<<32, 256, 0, stream>>>(mzi, trig);
        build_u<<<128, 64, 0, stream>>>(oph, trig, ufrag);
        const int nblk = (maxrow + 127) / 128;
        cgemm_main<<<nblk, 256, 0, stream>>>(fr, fi, ufrag, (float*)d_out,
                                             maxrow, 0);
    } else {
        // Fallback: stage inside d_out rows 0..511 (R5-R7 proven path).
        unsigned short* ufrag = (unsigned short*)d_out;          // rows 0..255
        float4* trig = (float4*)((float*)d_out + 32768);         // rows 256..511
        if (maxrow < 512) return;
        trig_k<<<32, 256, 0, stream>>>(mzi, trig);
        build_u<<<128, 64, 0, stream>>>(oph, trig, ufrag);
        const int nmain = (maxrow - 256 + 127) / 128;
        cgemm_main<<<nmain, 256, 0, stream>>>(fr, fi, ufrag, (float*)d_out,
                                              maxrow, 256);
        cgemm_tail<<<2, 256, 0, stream>>>(fr, fi, ufrag, (float*)d_out, maxrow);
    }
}